// Round 1
// baseline (768.000 us; speedup 1.0000x reference)
//
#include <hip/hip_runtime.h>
#include <math.h>

// Problem constants (from reference)
constexpr int R  = 5;
constexpr int E  = 50000;
constexpr int NU = 20000;
constexpr int NI = 20000;
constexpr int NF = 4;
constexpr int DN = 16;
constexpr int DR = 64;
constexpr int DO = 64;
constexpr float TAU = 0.5f;

// ---------------- Pass 1: one wave (64 lanes) per edge ----------------
// Computes blended[r,e]; atomically accumulates norm_user / norm_item.
__global__ __launch_bounds__(256) void pass1_kernel(
    const float* __restrict__ user_h,      // (NF,R,NU,DN)
    const float* __restrict__ item_h,      // (NF,R,NI,DN)
    const float* __restrict__ user_hsum,   // (R,NU,NF,DN)
    const float* __restrict__ item_hsum,   // (R,NI,NF,DN)
    const float* __restrict__ review_feat, // (R,E,NF,DR)
    const float* __restrict__ prototypes,  // (NF,DR)
    const float* __restrict__ eta,         // (R,E)
    const int*   __restrict__ edge_src,    // (R,E)
    const int*   __restrict__ edge_dst,    // (R,E)
    const int*   __restrict__ kptr,
    float* __restrict__ blended_out,       // (R*E)
    float* __restrict__ norm_user,         // (NU)
    float* __restrict__ norm_item)         // (NI)
{
    const int lane = threadIdx.x & 63;
    const int wid  = threadIdx.x >> 6;
    const long long idx = (long long)blockIdx.x * (blockDim.x >> 6) + wid;
    if (idx >= (long long)R * E) return;
    const int r = (int)(idx / E);
    const int e = (int)(idx - (long long)r * E);
    const int k = *kptr;
    const long long re = (long long)r * E + e;

    const int src = edge_src[re];
    const int dst = edge_dst[re];

    // ---- sim_k: normalized dot over DN=16 (lanes 0..15 active) ----
    float na = 0.f, nb = 0.f, ab = 0.f;
    if (lane < DN) {
        const float* up = user_h + (((long long)k * R + r) * NU + src) * DN;
        const float* ip = item_h + (((long long)k * R + r) * NI + dst) * DN;
        float a = up[lane];
        float b = ip[lane];
        na = a * a; nb = b * b; ab = a * b;
    }
#pragma unroll
    for (int m = 1; m < 16; m <<= 1) {
        na += __shfl_xor(na, m, 64);
        nb += __shfl_xor(nb, m, 64);
        ab += __shfl_xor(ab, m, 64);
    }
    na = __shfl(na, 0, 64);
    nb = __shfl(nb, 0, 64);
    ab = __shfl(ab, 0, 64);
    const float sim_k = ab / (fmaxf(sqrtf(na), 1e-12f) * fmaxf(sqrtf(nb), 1e-12f)) / TAU;

    // ---- sim_all over hsum rows (64 floats each, lane l -> element l) ----
    // element layout: f = lane>>4, d = lane&15
    const float* rs = user_hsum + ((long long)r * NU + src) * (NF * DN);
    const float* cs = item_hsum + ((long long)r * NI + dst) * (NF * DN);
    float p = rs[lane] * cs[lane];
#pragma unroll
    for (int m = 1; m < 16; m <<= 1) p += __shfl_xor(p, m, 64);
    // every lane of group f now holds sim_all[f] (pre /TAU)
    float es = __expf(p / TAU);
    float denom_sim = es;
    denom_sim += __shfl_xor(denom_sim, 16, 64);
    denom_sim += __shfl_xor(denom_sim, 32, 64);   // sum over 4 factor groups

    // ---- anchors: review_feat row = 256 floats, float4 per lane ----
    const float4* rf4 = (const float4*)(review_feat + re * (long long)(NF * DR));
    const float4* pr4 = (const float4*)prototypes;
    float4 rv = rf4[lane];
    float4 pv = pr4[lane];
    float q = rv.x * pv.x + rv.y * pv.y + rv.z * pv.z + rv.w * pv.w;
#pragma unroll
    for (int m = 1; m < 16; m <<= 1) q += __shfl_xor(q, m, 64);
    // group f (lane>>4) holds anchor_all[f] (pre /TAU)
    float ea = __expf(q / TAU);
    float denom_anc = ea;
    denom_anc += __shfl_xor(denom_anc, 16, 64);
    denom_anc += __shfl_xor(denom_anc, 32, 64);
    float ea_k = __shfl(ea, k * 16, 64);          // exp(anchor_all[k]) == exp(anchor_k)

    const float exp_anchor = ea_k / denom_anc;
    const float exp_sim    = __expf(sim_k) / denom_sim;
    const float g = 1.0f / (1.0f + __expf(-eta[re]));
    const float blended = g * exp_anchor + (1.0f - g) * exp_sim;

    if (lane == 0) {
        blended_out[re] = blended;
        atomicAdd(&norm_user[src], blended);
        atomicAdd(&norm_item[dst], blended);
    }
}

// ---------------- Pass 2: one thread per (edge, o), o in [0,16) ----------------
__global__ __launch_bounds__(256) void pass2_kernel(
    const float* __restrict__ user_h,
    const float* __restrict__ item_h,
    const float* __restrict__ review_feat,
    const float* __restrict__ node_w_fwd,    // (R,DN,DN)
    const float* __restrict__ review_w_fwd,  // (R,DN,DR)
    const float* __restrict__ node_w_rev,
    const float* __restrict__ review_w_rev,
    const int*   __restrict__ edge_src,
    const int*   __restrict__ edge_dst,
    const int*   __restrict__ kptr,
    const float* __restrict__ blended,
    const float* __restrict__ norm_user,
    const float* __restrict__ norm_item,
    float* __restrict__ user_msg,  // (NU,DN)
    float* __restrict__ item_msg,  // (NI,DN)
    float* __restrict__ int_dist)  // (R*E)
{
    const long long t = (long long)blockIdx.x * blockDim.x + threadIdx.x;
    if (t >= (long long)R * E * DN) return;
    const int o = (int)(t & 15);
    const long long re = t >> 4;
    const int r = (int)(re / E);
    const int k = *kptr;

    const int src = edge_src[re];
    const int dst = edge_dst[re];
    const float b = blended[re];
    const float w = b * rsqrtf(norm_user[src] * norm_item[dst]);
    if (o == 0) int_dist[re] = w;

    const float* up  = user_h + (((long long)k * R + r) * NU + src) * DN;
    const float* ip  = item_h + (((long long)k * R + r) * NI + dst) * DN;
    const float* nwf = node_w_fwd + ((long long)r * DN + o) * DN;
    const float* nwr = node_w_rev + ((long long)r * DN + o) * DN;

    float accf = 0.f, accr = 0.f;
#pragma unroll
    for (int d = 0; d < DN; ++d) {
        accf += up[d] * nwf[d];
        accr += ip[d] * nwr[d];
    }
    const float* rfk = review_feat + (re * NF + k) * (long long)DR;
    const float* rwf = review_w_fwd + ((long long)r * DN + o) * DR;
    const float* rwr = review_w_rev + ((long long)r * DN + o) * DR;
#pragma unroll
    for (int d = 0; d < DR; ++d) {
        float rv = rfk[d];
        accf += rv * rwf[d];
        accr += rv * rwr[d];
    }
    atomicAdd(&item_msg[(long long)dst * DN + o], accf * w);
    atomicAdd(&user_msg[(long long)src * DN + o], accr * w);
}

// ---------------- Pass 3: one thread per (node, j), users then items ----------------
__global__ __launch_bounds__(256) void pass3_kernel(
    const float* __restrict__ user_msg,
    const float* __restrict__ item_msg,
    const float* __restrict__ ufc_w,  // (DO,DN)
    const float* __restrict__ ufc_b,  // (DO)
    const float* __restrict__ ifc_w,
    const float* __restrict__ ifc_b,
    float* __restrict__ ufeat,        // (NU,DO)
    float* __restrict__ ifeat)        // (NI,DO)
{
    const long long t = (long long)blockIdx.x * blockDim.x + threadIdx.x;
    const long long nu_total = (long long)NU * DO;
    const long long total = nu_total + (long long)NI * DO;
    if (t >= total) return;
    const bool is_item = (t >= nu_total);
    const long long tt = is_item ? (t - nu_total) : t;
    const int j = (int)(tt & 63);         // DO == 64
    const long long n = tt >> 6;

    const float* msg  = (is_item ? item_msg : user_msg) + n * DN;
    const float* wrow = (is_item ? ifc_w : ufc_w) + (long long)j * DN;
    float acc = (is_item ? ifc_b : ufc_b)[j];
#pragma unroll
    for (int d = 0; d < DN; ++d) {
        float x = msg[d];
        x = (x > 0.f) ? x : 0.1f * x;
        acc += x * wrow[d];
    }
    (is_item ? ifeat : ufeat)[tt] = acc;
}

extern "C" void kernel_launch(void* const* d_in, const int* in_sizes, int n_in,
                              void* d_out, int out_size, void* d_ws, size_t ws_size,
                              hipStream_t stream) {
    const float* user_h       = (const float*)d_in[0];
    const float* item_h       = (const float*)d_in[1];
    const float* user_hsum    = (const float*)d_in[2];
    const float* item_hsum    = (const float*)d_in[3];
    const float* review_feat  = (const float*)d_in[4];
    const float* prototypes   = (const float*)d_in[5];
    const float* eta          = (const float*)d_in[6];
    const float* node_w_fwd   = (const float*)d_in[7];
    const float* review_w_fwd = (const float*)d_in[8];
    const float* node_w_rev   = (const float*)d_in[9];
    const float* review_w_rev = (const float*)d_in[10];
    const float* ufc_w        = (const float*)d_in[11];
    const float* ufc_b        = (const float*)d_in[12];
    const float* ifc_w        = (const float*)d_in[13];
    const float* ifc_b        = (const float*)d_in[14];
    const int*   edge_src     = (const int*)d_in[15];
    const int*   edge_dst     = (const int*)d_in[16];
    const int*   kptr         = (const int*)d_in[17];

    // Workspace layout (floats):
    // [0, NU)                      norm_user      (zeroed)
    // [NU, NU+NI)                  norm_item      (zeroed)
    // [NU+NI, +NU*DN)              user_msg       (zeroed)
    // [.., +NI*DN)                 item_msg       (zeroed)
    // [.., +R*E)                   blended        (fully overwritten)
    float* ws = (float*)d_ws;
    float* norm_user = ws;
    float* norm_item = norm_user + NU;
    float* user_msg  = norm_item + NI;
    float* item_msg  = user_msg + (long long)NU * DN;
    float* blended   = item_msg + (long long)NI * DN;

    const size_t zero_bytes = (size_t)(NU + NI + NU * DN + NI * DN) * sizeof(float);
    hipMemsetAsync(d_ws, 0, zero_bytes, stream);

    float* ufeat    = (float*)d_out;                       // NU*DO
    float* ifeat    = ufeat + (long long)NU * DO;          // NI*DO
    float* int_dist = ifeat + (long long)NI * DO;          // R*E

    // Pass 1: one wave per edge; 4 waves per 256-thread block
    {
        const long long nwaves = (long long)R * E;
        const int blocks = (int)((nwaves + 3) / 4);
        pass1_kernel<<<blocks, 256, 0, stream>>>(
            user_h, item_h, user_hsum, item_hsum, review_feat, prototypes,
            eta, edge_src, edge_dst, kptr, blended, norm_user, norm_item);
    }

    // Pass 2: one thread per (edge, o)
    {
        const long long nthreads = (long long)R * E * DN;
        const int blocks = (int)((nthreads + 255) / 256);
        pass2_kernel<<<blocks, 256, 0, stream>>>(
            user_h, item_h, review_feat, node_w_fwd, review_w_fwd,
            node_w_rev, review_w_rev, edge_src, edge_dst, kptr,
            blended, norm_user, norm_item, user_msg, item_msg, int_dist);
    }

    // Pass 3: one thread per output element
    {
        const long long nthreads = (long long)(NU + NI) * DO;
        const int blocks = (int)((nthreads + 255) / 256);
        pass3_kernel<<<blocks, 256, 0, stream>>>(
            user_msg, item_msg, ufc_w, ufc_b, ifc_w, ifc_b, ufeat, ifeat);
    }
}

// Round 2
// 561.143 us; speedup vs baseline: 1.3686x; 1.3686x over previous
//
#include <hip/hip_runtime.h>
#include <math.h>

// Problem constants (from reference)
constexpr int R  = 5;
constexpr int E  = 50000;
constexpr int NU = 20000;
constexpr int NI = 20000;
constexpr int NF = 4;
constexpr int DN = 16;
constexpr int DR = 64;
constexpr int DO = 64;
constexpr float TAU = 0.5f;

// ---------------- Pass 1: one wave (64 lanes) per edge ----------------
__global__ __launch_bounds__(256) void pass1_kernel(
    const float* __restrict__ user_h,      // (NF,R,NU,DN)
    const float* __restrict__ item_h,      // (NF,R,NI,DN)
    const float* __restrict__ user_hsum,   // (R,NU,NF,DN)
    const float* __restrict__ item_hsum,   // (R,NI,NF,DN)
    const float* __restrict__ review_feat, // (R,E,NF,DR)
    const float* __restrict__ prototypes,  // (NF,DR)
    const float* __restrict__ eta,         // (R,E)
    const int*   __restrict__ edge_src,    // (R,E)
    const int*   __restrict__ edge_dst,    // (R,E)
    const int*   __restrict__ kptr,
    float* __restrict__ blended_out,       // (R*E)
    float* __restrict__ norm_user,         // (NU)
    float* __restrict__ norm_item)         // (NI)
{
    const int lane = threadIdx.x & 63;
    const int wid  = threadIdx.x >> 6;
    const long long idx = (long long)blockIdx.x * (blockDim.x >> 6) + wid;
    if (idx >= (long long)R * E) return;
    const int r = (int)(idx / E);
    const int e = (int)(idx - (long long)r * E);
    const int k = *kptr;
    const long long re = (long long)r * E + e;

    const int src = edge_src[re];
    const int dst = edge_dst[re];

    // ---- sim_k: normalized dot over DN=16 (lanes 0..15 active) ----
    float na = 0.f, nb = 0.f, ab = 0.f;
    if (lane < DN) {
        const float* up = user_h + (((long long)k * R + r) * NU + src) * DN;
        const float* ip = item_h + (((long long)k * R + r) * NI + dst) * DN;
        float a = up[lane];
        float b = ip[lane];
        na = a * a; nb = b * b; ab = a * b;
    }
#pragma unroll
    for (int m = 1; m < 16; m <<= 1) {
        na += __shfl_xor(na, m, 64);
        nb += __shfl_xor(nb, m, 64);
        ab += __shfl_xor(ab, m, 64);
    }
    na = __shfl(na, 0, 64);
    nb = __shfl(nb, 0, 64);
    ab = __shfl(ab, 0, 64);
    const float sim_k = ab / (fmaxf(sqrtf(na), 1e-12f) * fmaxf(sqrtf(nb), 1e-12f)) / TAU;

    // ---- sim_all over hsum rows (64 floats each, lane l -> element l) ----
    const float* rs = user_hsum + ((long long)r * NU + src) * (NF * DN);
    const float* cs = item_hsum + ((long long)r * NI + dst) * (NF * DN);
    float p = rs[lane] * cs[lane];
#pragma unroll
    for (int m = 1; m < 16; m <<= 1) p += __shfl_xor(p, m, 64);
    float es = __expf(p / TAU);
    float denom_sim = es;
    denom_sim += __shfl_xor(denom_sim, 16, 64);
    denom_sim += __shfl_xor(denom_sim, 32, 64);

    // ---- anchors: review_feat row = 256 floats, float4 per lane ----
    const float4* rf4 = (const float4*)(review_feat + re * (long long)(NF * DR));
    const float4* pr4 = (const float4*)prototypes;
    float4 rv = rf4[lane];
    float4 pv = pr4[lane];
    float q = rv.x * pv.x + rv.y * pv.y + rv.z * pv.z + rv.w * pv.w;
#pragma unroll
    for (int m = 1; m < 16; m <<= 1) q += __shfl_xor(q, m, 64);
    float ea = __expf(q / TAU);
    float denom_anc = ea;
    denom_anc += __shfl_xor(denom_anc, 16, 64);
    denom_anc += __shfl_xor(denom_anc, 32, 64);
    float ea_k = __shfl(ea, k * 16, 64);

    const float exp_anchor = ea_k / denom_anc;
    const float exp_sim    = __expf(sim_k) / denom_sim;
    const float g = 1.0f / (1.0f + __expf(-eta[re]));
    const float blended = g * exp_anchor + (1.0f - g) * exp_sim;

    if (lane == 0) {
        blended_out[re] = blended;
        atomicAdd(&norm_user[src], blended);
        atomicAdd(&norm_item[dst], blended);
    }
}

// ---------------- Kernel A: dense node transform ----------------
// hu_t[r,n,o] = sum_d user_h[k,r,n,d] * node_w_fwd[r,o,d]   (side 0)
// hi_t[r,n,o] = sum_d item_h[k,r,n,d] * node_w_rev[r,o,d]   (side 1)
__global__ __launch_bounds__(256) void nodexf_kernel(
    const float* __restrict__ user_h,
    const float* __restrict__ item_h,
    const float* __restrict__ node_w_fwd,   // (R,DN,DN)
    const float* __restrict__ node_w_rev,   // (R,DN,DN)
    const int*   __restrict__ kptr,
    float* __restrict__ hu_t,               // (R,NU,DN)
    float* __restrict__ hi_t)               // (R,NI,DN)
{
    const int r    = blockIdx.y;
    const int side = blockIdx.z;
    const int n0   = blockIdx.x * 64;
    const int k    = *kptr;
    const int N    = side ? NI : NU;
    const float* h    = side ? item_h : user_h;
    const float* wsrc = side ? node_w_rev : node_w_fwd;
    float* out        = side ? hi_t : hu_t;

    __shared__ __align__(16) float lds_h[64 * 16];
    __shared__ float lds_w[16 * 17];

    const int t = threadIdx.x;
    // stage weights (256 floats), scalar, conflict-free padded layout
    {
        const int o = t >> 4, d = t & 15;
        lds_w[o * 17 + d] = wsrc[((long long)r * DN + o) * DN + d];
    }
    // stage 64 node rows (1024 floats) as float4, fully coalesced
    {
        const int row = t >> 2, c = t & 3;
        if (n0 + row < N) {
            const float4 v = *(const float4*)(h + (((long long)k * R + r) * N + n0 + row) * DN + c * 4);
            *(float4*)&lds_h[t * 4] = v;
        }
    }
    __syncthreads();

    const int o = t & 15;
#pragma unroll
    for (int p = 0; p < 4; ++p) {
        const int nl = p * 16 + (t >> 4);
        const int n = n0 + nl;
        if (n < N) {
            float acc = 0.f;
#pragma unroll
            for (int d = 0; d < DN; ++d)
                acc += lds_h[nl * 16 + d] * lds_w[o * 17 + d];
            out[((long long)r * N + n) * DN + o] = acc;
        }
    }
}

// ---------------- Pass 2b: per-edge review transform + scatter ----------------
// block = 256 threads = 16 edges x 16 outputs, loops over 8 tiles (128 edges)
__global__ __launch_bounds__(256) void pass2b_kernel(
    const float* __restrict__ hu_t,
    const float* __restrict__ hi_t,
    const float* __restrict__ review_feat,
    const float* __restrict__ review_w_fwd,  // (R,DN,DR)
    const float* __restrict__ review_w_rev,  // (R,DN,DR)
    const int*   __restrict__ edge_src,
    const int*   __restrict__ edge_dst,
    const int*   __restrict__ kptr,
    const float* __restrict__ blended,
    const float* __restrict__ norm_user,
    const float* __restrict__ norm_item,
    float* __restrict__ user_msg,  // (NU,DN)
    float* __restrict__ item_msg,  // (NI,DN)
    float* __restrict__ int_dist)  // (R*E)
{
    constexpr int EPB = 128, TILE = 16, WPAD = 68;
    const int r  = blockIdx.y;
    const int e0 = blockIdx.x * EPB;
    const int k  = *kptr;
    const int t  = threadIdx.x;

    __shared__ __align__(16) float wf[16 * WPAD];
    __shared__ __align__(16) float wr[16 * WPAD];
    __shared__ __align__(16) float rf[16 * WPAD];

    // stage review weights for this r, once per block (coalesced scalar)
    for (int i = t; i < 16 * 64; i += 256) {
        const int o = i >> 6, d = i & 63;
        wf[o * WPAD + d] = review_w_fwd[((long long)r * DN + o) * DR + d];
        wr[o * WPAD + d] = review_w_rev[((long long)r * DN + o) * DR + d];
    }
    __syncthreads();

    const int el = t >> 4;     // edge-local index in tile (also staging row)
    const int o  = t & 15;     // output index (also staging chunk)

    for (int tile = 0; tile < EPB / TILE; ++tile) {
        const int ee = e0 + tile * TILE + el;
        if (ee < E) {
            const float4 v = *(const float4*)(review_feat +
                (((long long)r * E + ee) * NF + k) * DR + o * 4);
            *(float4*)&rf[el * WPAD + o * 4] = v;
        }
        __syncthreads();
        if (ee < E) {
            const int re = r * E + ee;
            float accf = 0.f, accr = 0.f;
#pragma unroll
            for (int c = 0; c < 16; ++c) {
                const float4 a  = *(const float4*)&rf[el * WPAD + c * 4];
                const float4 bf = *(const float4*)&wf[o * WPAD + c * 4];
                const float4 br = *(const float4*)&wr[o * WPAD + c * 4];
                accf += a.x * bf.x + a.y * bf.y + a.z * bf.z + a.w * bf.w;
                accr += a.x * br.x + a.y * br.y + a.z * br.z + a.w * br.w;
            }
            const int src = edge_src[re];
            const int dst = edge_dst[re];
            accf += hu_t[((long long)r * NU + src) * DN + o];
            accr += hi_t[((long long)r * NI + dst) * DN + o];
            const float w = blended[re] * rsqrtf(norm_user[src] * norm_item[dst]);
            if (o == 0) int_dist[re] = w;
            atomicAdd(&item_msg[(long long)dst * DN + o], accf * w);
            atomicAdd(&user_msg[(long long)src * DN + o], accr * w);
        }
        __syncthreads();
    }
}

// ---------------- Pass 3: one thread per (node, j) ----------------
__global__ __launch_bounds__(256) void pass3_kernel(
    const float* __restrict__ user_msg,
    const float* __restrict__ item_msg,
    const float* __restrict__ ufc_w,  // (DO,DN)
    const float* __restrict__ ufc_b,  // (DO)
    const float* __restrict__ ifc_w,
    const float* __restrict__ ifc_b,
    float* __restrict__ ufeat,        // (NU,DO)
    float* __restrict__ ifeat)        // (NI,DO)
{
    const long long t = (long long)blockIdx.x * blockDim.x + threadIdx.x;
    const long long nu_total = (long long)NU * DO;
    const long long total = nu_total + (long long)NI * DO;
    if (t >= total) return;
    const bool is_item = (t >= nu_total);
    const long long tt = is_item ? (t - nu_total) : t;
    const int j = (int)(tt & 63);
    const long long n = tt >> 6;

    const float* msg  = (is_item ? item_msg : user_msg) + n * DN;
    const float* wrow = (is_item ? ifc_w : ufc_w) + (long long)j * DN;
    float acc = (is_item ? ifc_b : ufc_b)[j];
#pragma unroll
    for (int d = 0; d < DN; ++d) {
        float x = msg[d];
        x = (x > 0.f) ? x : 0.1f * x;
        acc += x * wrow[d];
    }
    (is_item ? ifeat : ufeat)[tt] = acc;
}

extern "C" void kernel_launch(void* const* d_in, const int* in_sizes, int n_in,
                              void* d_out, int out_size, void* d_ws, size_t ws_size,
                              hipStream_t stream) {
    const float* user_h       = (const float*)d_in[0];
    const float* item_h       = (const float*)d_in[1];
    const float* user_hsum    = (const float*)d_in[2];
    const float* item_hsum    = (const float*)d_in[3];
    const float* review_feat  = (const float*)d_in[4];
    const float* prototypes   = (const float*)d_in[5];
    const float* eta          = (const float*)d_in[6];
    const float* node_w_fwd   = (const float*)d_in[7];
    const float* review_w_fwd = (const float*)d_in[8];
    const float* node_w_rev   = (const float*)d_in[9];
    const float* review_w_rev = (const float*)d_in[10];
    const float* ufc_w        = (const float*)d_in[11];
    const float* ufc_b        = (const float*)d_in[12];
    const float* ifc_w        = (const float*)d_in[13];
    const float* ifc_b        = (const float*)d_in[14];
    const int*   edge_src     = (const int*)d_in[15];
    const int*   edge_dst     = (const int*)d_in[16];
    const int*   kptr         = (const int*)d_in[17];

    // Workspace layout (floats):
    // norm_user (NU), norm_item (NI), user_msg (NU*DN), item_msg (NI*DN)  <- zeroed
    // blended (R*E), hu_t (R*NU*DN), hi_t (R*NI*DN)                       <- overwritten
    float* ws = (float*)d_ws;
    float* norm_user = ws;
    float* norm_item = norm_user + NU;
    float* user_msg  = norm_item + NI;
    float* item_msg  = user_msg + (long long)NU * DN;
    float* blended   = item_msg + (long long)NI * DN;
    float* hu_t      = blended + (long long)R * E;
    float* hi_t      = hu_t + (long long)R * NU * DN;

    const size_t zero_bytes = (size_t)(NU + NI + NU * DN + NI * DN) * sizeof(float);
    hipMemsetAsync(d_ws, 0, zero_bytes, stream);

    float* ufeat    = (float*)d_out;
    float* ifeat    = ufeat + (long long)NU * DO;
    float* int_dist = ifeat + (long long)NI * DO;

    // Node transform: grid (node tiles, r, side)
    {
        dim3 grid((NU + 63) / 64, R, 2);
        nodexf_kernel<<<grid, 256, 0, stream>>>(
            user_h, item_h, node_w_fwd, node_w_rev, kptr, hu_t, hi_t);
    }

    // Pass 1: one wave per edge; 4 waves per 256-thread block
    {
        const long long nwaves = (long long)R * E;
        const int blocks = (int)((nwaves + 3) / 4);
        pass1_kernel<<<blocks, 256, 0, stream>>>(
            user_h, item_h, user_hsum, item_hsum, review_feat, prototypes,
            eta, edge_src, edge_dst, kptr, blended, norm_user, norm_item);
    }

    // Pass 2b: review transform + gather + scatter
    {
        dim3 grid((E + 127) / 128, R);
        pass2b_kernel<<<grid, 256, 0, stream>>>(
            hu_t, hi_t, review_feat, review_w_fwd, review_w_rev,
            edge_src, edge_dst, kptr, blended, norm_user, norm_item,
            user_msg, item_msg, int_dist);
    }

    // Pass 3
    {
        const long long nthreads = (long long)(NU + NI) * DO;
        const int blocks = (int)((nthreads + 255) / 256);
        pass3_kernel<<<blocks, 256, 0, stream>>>(
            user_msg, item_msg, ufc_w, ufc_b, ifc_w, ifc_b, ufeat, ifeat);
    }
}